// Round 11
// baseline (221.400 us; speedup 1.0000x reference)
//
#include <hip/hip_runtime.h>

#define M 4096
#define L 32
#define K 64
#define NBLK 64
#define BLOCK 1024
#define NPW 4                 // nodes per wave
#define NPB 64                // nodes per block (16 waves x 4)
#define D 4                   // weight-prefetch pipeline depth (layers)
#define MK (M * K)
#define FB 0xAAAAAAAAu        // ws poison; round tag = FB + r (r>=1)

// R11: block-staged tagged exchange (R8, best-known) + DEEP weight pipeline.
// Diagnosis R7-R10: dur ~= hbm_bytes/BW every round; the w+igraf stream
// (2 MB/layer) runs at ~400 GB/s because each layer's fragments are fetched
// with ~1 round of slack (low outstanding-request duty cycle). Fix: D=4
// register pipeline -> every fragment load has 4 rounds to complete; the
// stream leaves the critical path. Also 64x1024 blocks: same 1024 waves
// (same concurrency) but restage traffic drops 8 -> 2 MB/layer.
//
// Exchange (verified R8-R10): v_r[node] published as ONE aligned 8B sc1
// store (FB+r)<<32|f32bits — tag visible <=> value visible. Restage: 4
// strided u64 sc1 loads/thread (coalesced 512B/wave-instr), verify tags,
// re-load only stale. Double-buffered exchange + double-buffered LDS sv,
// ONE __syncthreads per round. Blocks provably <2 rounds apart. Poison
// hi-word FB+0 never matches a tag -> no memset dispatch.
__global__ __launch_bounds__(BLOCK)
void net_kernel(const float* __restrict__ x,
                const float* __restrict__ w_in,
                const float* __restrict__ b_in,
                const float* __restrict__ w,
                const float* __restrict__ b,
                const int* __restrict__ igraf,
                float* __restrict__ out,
                unsigned long long* __restrict__ buf)   // 2 x M u64
{
    __shared__ float sv[2][M];   // double-buffered value vector (32 KB)

    const int tid  = threadIdx.x;
    const int blk  = blockIdx.x;
    const int wave = tid >> 6;
    const int lane = tid & 63;
    const int base = blk * NPB + wave * NPW;
    const bool finblk = (blk == NBLK - 1);   // owns node M-1

    // ---- v0 input loads first (oldest in queue: their wait won't drain
    //      the pipeline fill below) ----
    float4 x4[4], wi[4], bi[4];
    #pragma unroll
    for (int j = 0; j < 4; ++j) {
        const int idx = tid + j * BLOCK;
        x4[j] = ((const float4*)x)[idx];
        wi[j] = ((const float4*)w_in)[idx];
        bi[j] = ((const float4*)b_in)[idx];
    }
    __asm__ volatile("" ::: "memory");

    // ---- fill the D-deep fragment pipeline (layers 0..3) ----
    float wbuf[D][NPW]; int ibuf[D][NPW]; float bbuf[D];
    #pragma unroll
    for (int d = 0; d < D; ++d) {
        const size_t o = (size_t)d * MK + (size_t)base * K + (size_t)lane;
        #pragma unroll
        for (int j = 0; j < NPW; ++j) {
            wbuf[d][j] = w[o + (size_t)j * K];
            ibuf[d][j] = igraf[o + (size_t)j * K];
        }
        bbuf[d] = (lane < NPW) ? b[d * M + base + lane] : 0.0f;
    }

    // ---- v0 = relu(w_in*x + b_in) into sv[0] ----
    #pragma unroll
    for (int j = 0; j < 4; ++j) {
        const int idx = tid + j * BLOCK;
        float4 r;
        r.x = fmaxf(fmaf(wi[j].x, x4[j].x, bi[j].x), 0.0f);
        r.y = fmaxf(fmaf(wi[j].y, x4[j].y, bi[j].y), 0.0f);
        r.z = fmaxf(fmaf(wi[j].z, x4[j].z, bi[j].z), 0.0f);
        r.w = fmaxf(fmaf(wi[j].w, x4[j].w, bi[j].w), 0.0f);
        ((float4*)sv[0])[idx] = r;
    }
    __syncthreads();

    int cur = 0;
    for (int g = 0; g < L / D; ++g) {
        #pragma unroll
        for (int s = 0; s < D; ++s) {
            const int l = g * D + s;

            // Gather + product from sv[cur], slot s fragments.
            float p[NPW];
            #pragma unroll
            for (int j = 0; j < NPW; ++j)
                p[j] = wbuf[s][j] * sv[cur][ibuf[s][j]];

            // 4 independent 64-lane butterfly reductions.
            #pragma unroll
            for (int j = 0; j < NPW; ++j) {
                #pragma unroll
                for (int off = 32; off > 0; off >>= 1)
                    p[j] += __shfl_xor(p[j], off, 64);
            }

            float pj = p[0];
            pj = (lane == 1) ? p[1] : pj;
            pj = (lane == 2) ? p[2] : pj;
            pj = (lane == 3) ? p[3] : pj;
            const float val = 1.0f / (1.0f + __expf(-(pj + bbuf[s])));

            if (l == L - 1) {
                // Only block 63 reaches l=31; node 4095 = wave 15, lane 3.
                if (wave == 15 && lane == 3) out[0] = val;
                return;
            }

            const unsigned tag = FB + (unsigned)(l + 1);
            unsigned long long* bufr = buf + (size_t)((l + 1) & 1) * M;

            // Publish: tagged 8B store, fire-and-forget.
            if (lane < NPW) {
                const unsigned long long pk =
                    ((unsigned long long)tag << 32) |
                    (unsigned long long)__float_as_uint(val);
                __hip_atomic_store(&bufr[base + lane], pk,
                                   __ATOMIC_RELAXED, __HIP_MEMORY_SCOPE_AGENT);
            }

            if (l == L - 2 && !finblk) return;   // all but block 63 done

            // Tag loads FIRST (verify waits only on these; refill stays
            // outstanding through the wait).
            unsigned long long vals[4];
            #pragma unroll
            for (int j = 0; j < 4; ++j)
                vals[j] = __hip_atomic_load(&bufr[tid + j * BLOCK],
                                            __ATOMIC_RELAXED,
                                            __HIP_MEMORY_SCOPE_AGENT);
            __asm__ volatile("" ::: "memory");   // pin refill AFTER tag loads

            // Refill slot s for layer l+D: 4 rounds of slack to complete.
            if (l + D < L) {
                const size_t o = (size_t)(l + D) * MK
                               + (size_t)base * K + (size_t)lane;
                #pragma unroll
                for (int j = 0; j < NPW; ++j) {
                    wbuf[s][j] = w[o + (size_t)j * K];
                    ibuf[s][j] = igraf[o + (size_t)j * K];
                }
                if (lane < NPW) bbuf[s] = b[(l + D) * M + base + lane];
            }

            // Verify tags; re-load only stale entries (pure mall-RTT).
            for (;;) {
                bool ok = true;
                #pragma unroll
                for (int j = 0; j < 4; ++j) {
                    if ((unsigned)(vals[j] >> 32) != tag) {
                        ok = false;
                        vals[j] = __hip_atomic_load(&bufr[tid + j * BLOCK],
                                                    __ATOMIC_RELAXED,
                                                    __HIP_MEMORY_SCOPE_AGENT);
                    }
                }
                if (ok) break;
                __builtin_amdgcn_s_sleep(1);
            }

            // Stage into the other LDS buffer; ONE sync per round.
            const int nxt = cur ^ 1;
            #pragma unroll
            for (int j = 0; j < 4; ++j)
                sv[nxt][tid + j * BLOCK] =
                    __uint_as_float((unsigned)vals[j]);
            __syncthreads();
            cur = nxt;
        }
    }
}

extern "C" void kernel_launch(void* const* d_in, const int* in_sizes, int n_in,
                              void* d_out, int out_size, void* d_ws, size_t ws_size,
                              hipStream_t stream) {
    const float* x     = (const float*)d_in[0];
    const float* w_in  = (const float*)d_in[1];
    const float* b_in  = (const float*)d_in[2];
    const float* wt    = (const float*)d_in[3];
    const float* b     = (const float*)d_in[4];
    const int*   igraf = (const int*)d_in[5];
    float*       out   = (float*)d_out;

    unsigned long long* buf = (unsigned long long*)d_ws;   // 2 x M x 8B = 64KB

    // No memset: poison hi-word = FB+0 never matches a round tag (FB+r, r>=1).
    hipLaunchKernelGGL(net_kernel, dim3(NBLK), dim3(BLOCK), 0, stream,
                       x, w_in, b_in, wt, b, igraf, out, buf);
    (void)in_sizes; (void)n_in; (void)out_size; (void)ws_size;
}